// Round 15
// baseline (9546.749 us; speedup 1.0000x reference)
//
#include <hip/hip_runtime.h>

typedef unsigned short u16;
typedef unsigned long long u64;
typedef __attribute__((ext_vector_type(8))) short short8;
typedef __attribute__((ext_vector_type(4))) float f32x4;

#define DEVINL __device__ __forceinline__

constexpr int Nb = 64;     // batch
constexpr int Tt = 1024;   // time
constexpr int Dd = 1024;   // input dim
constexpr int Hh = 1024;   // hidden
constexpr int NWG = 256;   // workgroups (== CUs)
constexpr int TPB = 256;   // threads per wg (4 waves)
constexpr int TWG = 128;   // wgs per team
constexpr int MS  = 32;    // samples per team

DEVINL u16 f2b(float f) {
  union { float f; unsigned u; } v; v.f = f;
  unsigned r = (v.u + 0x7fffu + ((v.u >> 16) & 1u)) >> 16;
  return (u16)r;
}
DEVINL float sigm(float x) { return 1.f / (1.f + __expf(-x)); }
DEVINL float tanhfast(float x) { float e = __expf(2.f * x); return 1.f - 2.f / (e + 1.f); }

// IC-coherent (SC1) h-fragment load (fallback path only).
DEVINL short8 ldh16(const u16* p) {
  u64 a = __hip_atomic_load((const u64*)p,       __ATOMIC_RELAXED, __HIP_MEMORY_SCOPE_AGENT);
  u64 b = __hip_atomic_load((const u64*)(p + 4), __ATOMIC_RELAXED, __HIP_MEMORY_SCOPE_AGENT);
  union { u64 q[2]; short8 v; } u;
  u.q[0] = a; u.q[1] = b;
  return u.v;
}

// Raw LDS barrier: lgkmcnt drain + s_barrier; does NOT drain vmcnt.
DEVINL void bar_w() {
  asm volatile("s_waitcnt lgkmcnt(0)" ::: "memory");
  __builtin_amdgcn_s_barrier();
}

__global__ void cvt_x_kernel(const float* __restrict__ x, u16* __restrict__ xb) {
  size_t i = ((size_t)blockIdx.x * TPB + threadIdx.x) * 8;
  float4 a = *reinterpret_cast<const float4*>(x + i);
  float4 b = *reinterpret_cast<const float4*>(x + i + 4);
  short8 r;
  r[0] = (short)f2b(a.x); r[1] = (short)f2b(a.y);
  r[2] = (short)f2b(a.z); r[3] = (short)f2b(a.w);
  r[4] = (short)f2b(b.x); r[5] = (short)f2b(b.y);
  r[6] = (short)f2b(b.z); r[7] = (short)f2b(b.w);
  *reinterpret_cast<short8*>(xb + i) = r;
}

// r10-proven structure (best known: 5.64 ms) + r15 flag-prefetch.
// 2 teams x 128 wgs; team owns 32 samples, wg owns 8 h-cols.
// HIST: producers publish h via relaxed SC1 stores (write-through to IC);
// consumers read fresh-address hist slots with NORMAL CACHED loads.
// Per step: FLAG PREFETCH (monotonic epochs -> an early read >= ep stays
// valid; steady-state gate resolves from a register, zero serial IC RTT
// post-MFMA) -> x-frag loads -> x MFMAs (hide under wait) -> Gate A
// (fresh polls only on miss) -> Gate B (pubcnt WAR) -> cached h loads ->
// h MFMAs -> psum LDS reduce (one raw barrier) -> gates -> symmetric
// publish (per-wave SC1 store + own vmcnt drain + pubcnt; 4th wave flags).
template<bool XBF16, bool HIST>
__global__ __launch_bounds__(TPB, 1) void lstm_team(
    const float* __restrict__ x, const u16* __restrict__ xb,
    const float* __restrict__ h0, const float* __restrict__ Wx,
    const float* __restrict__ Wh, const float* __restrict__ bias,
    float* __restrict__ out, u16* __restrict__ hmem,
    unsigned* __restrict__ flg)
{
  __shared__ u16 Bt[32][2048];       // 128 KiB (init staging only)
  __shared__ float ex[4][32][36];    // 18 KiB partial-sum exchange
  __shared__ unsigned pubcnt;        // per-wg publish counter (monotonic)

  const int g   = blockIdx.x;
  const int tid = threadIdx.x;
  const int w   = tid >> 6;
  const int l   = tid & 63;

  const int team = ((g & 7) < 4) ? 0 : 1;
  const int r    = (g >> 3) * 4 + (g & 3);  // rank in team, 0..127
  const int n0   = team * MS;
  const int jc0  = r * 8;                   // this wg's 8 h-columns

  unsigned* tFlg = flg + team * TWG;        // 128 epochs, 4 cache lines
  u16* hb0 = HIST ? hmem + (size_t)team * ((size_t)Tt * MS * Hh)
                  : hmem + (size_t)team * (2 * MS * Hh);

  if (tid == 0) pubcnt = 0u;

  // ---- one-time: [Wh;Wx] column slice -> LDS bf16, swizzled ----
  for (int idx = tid; idx < 32 * 2048; idx += TPB) {
    int k = idx >> 5;
    int c = idx & 31;
    int pc = (c >> 3) * 1024 + jc0 + (c & 7);
    float v = (k < 1024) ? Wh[(size_t)k * 4096 + pc]
                         : Wx[(size_t)(k - 1024) * 4096 + pc];
    Bt[c][k ^ ((c & 7) << 3)] = f2b(v);
  }

  // ---- one-time init: WAVE 0 ONLY (vmcnt is per-wave; its drain must
  //      cover every init store before the flag) ----
  if (tid < 64) {
    int n  = tid >> 1;
    int jc = (tid & 1) * 4;
    const float* hp = h0 + (size_t)(n0 + n) * Hh + jc0 + jc;
    u64 pk = (u64)f2b(hp[0]) | ((u64)f2b(hp[1]) << 16) |
             ((u64)f2b(hp[2]) << 32) | ((u64)f2b(hp[3]) << 48);
    __hip_atomic_store((u64*)(hb0 + n * Hh + jc0 + jc), pk,
                       __ATOMIC_RELAXED, __HIP_MEMORY_SCOPE_AGENT);
    asm volatile("s_waitcnt vmcnt(0)" ::: "memory");
    if (tid == 0)
      __hip_atomic_store(&tFlg[r], 1u, __ATOMIC_RELAXED, __HIP_MEMORY_SCOPE_AGENT);
  }
  __syncthreads();  // Bt + pubcnt ready (one-time full sync)

  // epilogue roles: thread owns (nE = tid>>3, jj = tid&7)
  const int jj = tid & 7;
  const int nE = tid >> 3;
  const float bI = bias[0 * 1024 + jc0 + jj];
  const float bF = bias[1 * 1024 + jc0 + jj];
  const float bO = bias[2 * 1024 + jc0 + jj];
  const float bG = bias[3 * 1024 + jc0 + jj];
  float c_reg = 0.f;

  // MFMA lane roles; wave owns K-slice [256w, 256w+256)
  const int arow = l & 15;
  const int kg   = (l >> 4) * 8;
  const int kb   = w * 256;
  const int sw   = (l & 7) << 3;
  const u16* bp0 = &Bt[l & 15][0];
  const u16* bp1 = &Bt[16 | (l & 15)][0];

  // ---- hoist loop-invariant B-fragments ----
  short8 bh0[8], bh1[8], bx0[8], bx1[8];
  #pragma unroll
  for (int i = 0; i < 8; ++i) {
    int ka = (kb + kg + 32 * i) ^ sw;
    bh0[i] = *reinterpret_cast<const short8*>(bp0 + ka);
    bh1[i] = *reinterpret_cast<const short8*>(bp1 + ka);
    int kx = (1024 + kb + kg + 32 * i) ^ sw;
    bx0[i] = *reinterpret_cast<const short8*>(bp0 + kx);
    bx1[i] = *reinterpret_cast<const short8*>(bp1 + kx);
  }

  for (int t = 0; t < Tt; ++t) {
    const u16* hb  = HIST ? hb0 + (size_t)t * (MS * Hh) : hb0 + (t & 1) * (MS * Hh);
    u16*       hbn = HIST ? hb0 + (size_t)(t + 1) * (MS * Hh) : hb0 + ((t + 1) & 1) * (MS * Hh);

    // ---- r15: FLAG PREFETCH (earliest possible issue; epochs monotonic
    //      so a satisfying early read stays valid at the gate) ----
    unsigned f_pre = 0xFFFFFFFFu;
    if (l < 32)
      f_pre = __hip_atomic_load(&tFlg[32 * w + l], __ATOMIC_RELAXED,
                                __HIP_MEMORY_SCOPE_AGENT);

    // ---- x-fragment loads (pre-gate; latency hides under wait) ----
    short8 xv0[8], xv1[8];
    if constexpr (XBF16) {
      const u16* xr0 = xb + ((size_t)(n0 + arow)      * Tt + t) * Dd + kb + kg;
      const u16* xr1 = xb + ((size_t)(n0 + 16 + arow) * Tt + t) * Dd + kb + kg;
      #pragma unroll
      for (int i = 0; i < 8; ++i) {
        xv0[i] = *reinterpret_cast<const short8*>(xr0 + 32 * i);
        xv1[i] = *reinterpret_cast<const short8*>(xr1 + 32 * i);
      }
    } else {
      const float* xr0 = x + ((size_t)(n0 + arow)      * Tt + t) * Dd + kb + kg;
      const float* xr1 = x + ((size_t)(n0 + 16 + arow) * Tt + t) * Dd + kb + kg;
      #pragma unroll
      for (int i = 0; i < 8; ++i) {
        float4 a0 = *reinterpret_cast<const float4*>(xr0 + 32 * i);
        float4 a1 = *reinterpret_cast<const float4*>(xr0 + 32 * i + 4);
        float4 c0 = *reinterpret_cast<const float4*>(xr1 + 32 * i);
        float4 c1 = *reinterpret_cast<const float4*>(xr1 + 32 * i + 4);
        short8 v0, v1;
        v0[0]=(short)f2b(a0.x); v0[1]=(short)f2b(a0.y);
        v0[2]=(short)f2b(a0.z); v0[3]=(short)f2b(a0.w);
        v0[4]=(short)f2b(a1.x); v0[5]=(short)f2b(a1.y);
        v0[6]=(short)f2b(a1.z); v0[7]=(short)f2b(a1.w);
        v1[0]=(short)f2b(c0.x); v1[1]=(short)f2b(c0.y);
        v1[2]=(short)f2b(c0.z); v1[3]=(short)f2b(c0.w);
        v1[4]=(short)f2b(c1.x); v1[5]=(short)f2b(c1.y);
        v1[6]=(short)f2b(c1.z); v1[7]=(short)f2b(c1.w);
        xv0[i] = v0; xv1[i] = v1;
      }
    }

    f32x4 a00 = {0.f,0.f,0.f,0.f}, a01 = {0.f,0.f,0.f,0.f};
    f32x4 a10 = {0.f,0.f,0.f,0.f}, a11 = {0.f,0.f,0.f,0.f};

    // ---- x MFMAs PRE-gate (independent of h_t) ----
    #pragma unroll
    for (int i = 0; i < 8; ++i) {
      a00 = __builtin_amdgcn_mfma_f32_16x16x32_bf16(xv0[i], bx0[i], a00, 0, 0, 0);
      a01 = __builtin_amdgcn_mfma_f32_16x16x32_bf16(xv0[i], bx1[i], a01, 0, 0, 0);
      a10 = __builtin_amdgcn_mfma_f32_16x16x32_bf16(xv1[i], bx0[i], a10, 0, 0, 0);
      a11 = __builtin_amdgcn_mfma_f32_16x16x32_bf16(xv1[i], bx1[i], a11, 0, 0, 0);
    }

    // ---- Gate A: prefetched check first; fresh polls only on miss ----
    {
      const unsigned ep = (unsigned)(t + 1);
      bool rdy = (bool)__all(f_pre >= ep);
      while (!rdy) {
        unsigned f = 0xFFFFFFFFu;
        if (l < 32)
          f = __hip_atomic_load(&tFlg[32 * w + l], __ATOMIC_RELAXED,
                                __HIP_MEMORY_SCOPE_AGENT);
        rdy = (bool)__all(f >= ep);
        if (!rdy) __builtin_amdgcn_s_sleep(1);
      }
    }
    // ---- Gate B: own-wg waves finished prior iteration (ex WAR safety) ----
    while (__hip_atomic_load(&pubcnt, __ATOMIC_RELAXED,
                             __HIP_MEMORY_SCOPE_WORKGROUP) < (unsigned)(4 * t))
      __builtin_amdgcn_s_sleep(1);
    asm volatile("" ::: "memory");  // keep h loads below the gates

    // ---- h loads: HIST -> normal cached (fresh addr) ----
    short8 hv0[8], hv1[8];
    {
      const u16* hr = hb + (size_t)arow * Hh + kb + kg;
      #pragma unroll
      for (int i = 0; i < 8; ++i) {
        if constexpr (HIST) {
          hv0[i] = *reinterpret_cast<const short8*>(hr + 32 * i);
          hv1[i] = *reinterpret_cast<const short8*>(hr + 16 * Hh + 32 * i);
        } else {
          hv0[i] = ldh16(hr + 32 * i);
          hv1[i] = ldh16(hr + 16 * Hh + 32 * i);
        }
      }
    }

    // ---- h MFMAs ----
    #pragma unroll
    for (int i = 0; i < 8; ++i) {
      a00 = __builtin_amdgcn_mfma_f32_16x16x32_bf16(hv0[i], bh0[i], a00, 0, 0, 0);
      a01 = __builtin_amdgcn_mfma_f32_16x16x32_bf16(hv0[i], bh1[i], a01, 0, 0, 0);
      a10 = __builtin_amdgcn_mfma_f32_16x16x32_bf16(hv1[i], bh0[i], a10, 0, 0, 0);
      a11 = __builtin_amdgcn_mfma_f32_16x16x32_bf16(hv1[i], bh1[i], a11, 0, 0, 0);
    }

    // ---- partial sums -> LDS ----
    #pragma unroll
    for (int q = 0; q < 4; ++q) {
      ex[w][ 0 + (l >> 4) * 4 + q][ 0 + (l & 15)] = a00[q];
      ex[w][ 0 + (l >> 4) * 4 + q][16 + (l & 15)] = a01[q];
      ex[w][16 + (l >> 4) * 4 + q][ 0 + (l & 15)] = a10[q];
      ex[w][16 + (l >> 4) * 4 + q][16 + (l & 15)] = a11[q];
    }
    bar_w();  // the ONLY per-step barrier

    // ---- gates, state update (thread owns row nE, col jj) ----
    float pI = bI, pF = bF, pO = bO, pG = bG;
    #pragma unroll
    for (int wv = 0; wv < 4; ++wv) {
      pI += ex[wv][nE][ 0 + jj];
      pF += ex[wv][nE][ 8 + jj];
      pO += ex[wv][nE][16 + jj];
      pG += ex[wv][nE][24 + jj];
    }
    const float ig = sigm(pI), fg = sigm(pF), og = sigm(pO);
    const float gg = tanhfast(pG);
    c_reg = fg * c_reg + ig * gg;
    const float hv = og * tanhfast(c_reg);

    // ---- symmetric publish: lane-pair u32 SC1 store of own h ----
    {
      int hb16 = (int)f2b(hv);
      int pb   = __shfl_xor(hb16, 1, 64);   // partner holds jj^1
      if ((tid & 1) == 0) {
        unsigned pk = (unsigned)(hb16 & 0xFFFF) | ((unsigned)(pb & 0xFFFF) << 16);
        __hip_atomic_store((unsigned*)(hbn + nE * Hh + jc0 + jj), pk,
                           __ATOMIC_RELAXED, __HIP_MEMORY_SCOPE_AGENT);
      }
      asm volatile("s_waitcnt vmcnt(0)" ::: "memory");  // own stores ACKed
      if (l == 0) {
        unsigned old = __hip_atomic_fetch_add(&pubcnt, 1u, __ATOMIC_RELAXED,
                                              __HIP_MEMORY_SCOPE_WORKGROUP);
        if (old == (unsigned)(4 * t + 3) && t + 1 < Tt)   // 4th wave: flag
          __hip_atomic_store(&tFlg[r], (unsigned)(t + 2),
                             __ATOMIC_RELAXED, __HIP_MEMORY_SCOPE_AGENT);
      }
    }

    // ---- out store (off critical path; drained ~1 step later) ----
    out[((size_t)(n0 + nE) * Tt + t) * Hh + jc0 + jj] = hv;
  }
}

extern "C" void kernel_launch(void* const* d_in, const int* in_sizes, int n_in,
                              void* d_out, int out_size, void* d_ws, size_t ws_size,
                              hipStream_t stream) {
  const float* x    = (const float*)d_in[0];
  const float* h0   = (const float*)d_in[1];
  const float* Wx   = (const float*)d_in[2];
  const float* Wh   = (const float*)d_in[3];
  const float* bias = (const float*)d_in[4];
  float* out = (float*)d_out;

  char* wsb = (char*)d_ws;
  unsigned* flg = (unsigned*)wsb;                  // 2 teams x 128 u32 = 1 KiB

  const size_t hist_off   = (size_t)1 << 20;
  const size_t hist_bytes = (size_t)2 * Tt * MS * Hh * 2;       // 128 MiB
  const size_t xb_bytes   = (size_t)Nb * Tt * Dd * 2;           // 128 MiB

  const bool use_hist = ws_size >= hist_off + hist_bytes;
  const size_t xb_off = use_hist ? hist_off + hist_bytes : hist_off;
  const bool use_xb   = ws_size >= xb_off + xb_bytes;

  u16* hmem = use_hist ? (u16*)(wsb + hist_off) : (u16*)(wsb + 65536);
  u16* xb   = (u16*)(wsb + xb_off);

  hipMemsetAsync(wsb, 0, 40960, stream);           // clear flags each launch

  void* args[] = {(void*)&x, (void*)&xb, (void*)&h0, (void*)&Wx, (void*)&Wh,
                  (void*)&bias, (void*)&out, (void*)&hmem, (void*)&flg};
  if (use_xb)
    cvt_x_kernel<<<dim3((Nb * Tt * Dd) / (8 * TPB)), dim3(TPB), 0, stream>>>(x, xb);

  const void* kfn =
      use_hist ? (use_xb ? (const void*)lstm_team<true, true>
                         : (const void*)lstm_team<false, true>)
               : (use_xb ? (const void*)lstm_team<true, false>
                         : (const void*)lstm_team<false, false>);
  hipLaunchCooperativeKernel(kfn, dim3(NWG), dim3(TPB), args, 0, stream);
}

// Round 16
// 5630.029 us; speedup vs baseline: 1.6957x; 1.6957x over previous
//
#include <hip/hip_runtime.h>

typedef unsigned short u16;
typedef unsigned long long u64;
typedef __attribute__((ext_vector_type(8))) short short8;
typedef __attribute__((ext_vector_type(4))) float f32x4;

#define DEVINL __device__ __forceinline__

constexpr int Nb = 64;     // batch
constexpr int Tt = 1024;   // time
constexpr int Dd = 1024;   // input dim
constexpr int Hh = 1024;   // hidden
constexpr int NWG = 256;   // workgroups (== CUs)
constexpr int TPB = 256;   // threads per wg (4 waves)
constexpr int TWG = 128;   // wgs per team
constexpr int MS  = 32;    // samples per team

DEVINL u16 f2b(float f) {
  union { float f; unsigned u; } v; v.f = f;
  unsigned r = (v.u + 0x7fffu + ((v.u >> 16) & 1u)) >> 16;
  return (u16)r;
}
DEVINL float sigm(float x) { return 1.f / (1.f + __expf(-x)); }
DEVINL float tanhfast(float x) { float e = __expf(2.f * x); return 1.f - 2.f / (e + 1.f); }

// IC-coherent (SC1) h-fragment load (fallback path only).
DEVINL short8 ldh16(const u16* p) {
  u64 a = __hip_atomic_load((const u64*)p,       __ATOMIC_RELAXED, __HIP_MEMORY_SCOPE_AGENT);
  u64 b = __hip_atomic_load((const u64*)(p + 4), __ATOMIC_RELAXED, __HIP_MEMORY_SCOPE_AGENT);
  union { u64 q[2]; short8 v; } u;
  u.q[0] = a; u.q[1] = b;
  return u.v;
}

// Raw LDS barrier: lgkmcnt drain + s_barrier; does NOT drain vmcnt.
DEVINL void bar_w() {
  asm volatile("s_waitcnt lgkmcnt(0)" ::: "memory");
  __builtin_amdgcn_s_barrier();
}

__global__ void cvt_x_kernel(const float* __restrict__ x, u16* __restrict__ xb) {
  size_t i = ((size_t)blockIdx.x * TPB + threadIdx.x) * 8;
  float4 a = *reinterpret_cast<const float4*>(x + i);
  float4 b = *reinterpret_cast<const float4*>(x + i + 4);
  short8 r;
  r[0] = (short)f2b(a.x); r[1] = (short)f2b(a.y);
  r[2] = (short)f2b(a.z); r[3] = (short)f2b(a.w);
  r[4] = (short)f2b(b.x); r[5] = (short)f2b(b.y);
  r[6] = (short)f2b(b.z); r[7] = (short)f2b(b.w);
  *reinterpret_cast<short8*>(xb + i) = r;
}

// 2 teams x 128 wgs; team owns 32 samples, wg owns 8 h-cols.
// HIST: producers publish h via relaxed SC1 stores (write-through to IC);
// consumers read fresh-address hist slots with NORMAL CACHED loads.
// r10 chain cuts: (1) x-MFMAs PRE-gate; (2) symmetric publish — each wave
// SC1-stores its own rows, own vmcnt(0), LDS pubcnt++; 4th wave stores the
// wg flag (ordered after all 4 waves' data ACKs); (3) SYNC2 removed — ex
// WAR safety via Gate B (pubcnt >= 4t: own waves finished prior iter).
// Flag invariant (r6): flag[r]==e => h cols [8r,8r+8) of slot e-1 hold
// h_{e-1} for all 32 rows (init included). Wave w polls wgs [32w,32w+32).
template<bool XBF16, bool HIST>
__global__ __launch_bounds__(TPB, 1) void lstm_team(
    const float* __restrict__ x, const u16* __restrict__ xb,
    const float* __restrict__ h0, const float* __restrict__ Wx,
    const float* __restrict__ Wh, const float* __restrict__ bias,
    float* __restrict__ out, u16* __restrict__ hmem,
    unsigned* __restrict__ flg)
{
  __shared__ u16 Bt[32][2048];       // 128 KiB (init staging only)
  __shared__ float ex[4][32][36];    // 18 KiB partial-sum exchange
  __shared__ unsigned pubcnt;        // per-wg publish counter (monotonic)

  const int g   = blockIdx.x;
  const int tid = threadIdx.x;
  const int w   = tid >> 6;
  const int l   = tid & 63;

  const int team = ((g & 7) < 4) ? 0 : 1;
  const int r    = (g >> 3) * 4 + (g & 3);  // rank in team, 0..127
  const int n0   = team * MS;
  const int jc0  = r * 8;                   // this wg's 8 h-columns

  unsigned* tFlg = flg + team * TWG;        // 128 epochs, 4 cache lines
  u16* hb0 = HIST ? hmem + (size_t)team * ((size_t)Tt * MS * Hh)
                  : hmem + (size_t)team * (2 * MS * Hh);

  if (tid == 0) pubcnt = 0u;

  // ---- one-time: [Wh;Wx] column slice -> LDS bf16, swizzled ----
  for (int idx = tid; idx < 32 * 2048; idx += TPB) {
    int k = idx >> 5;
    int c = idx & 31;
    int pc = (c >> 3) * 1024 + jc0 + (c & 7);
    float v = (k < 1024) ? Wh[(size_t)k * 4096 + pc]
                         : Wx[(size_t)(k - 1024) * 4096 + pc];
    Bt[c][k ^ ((c & 7) << 3)] = f2b(v);
  }

  // ---- one-time init, SAME ownership as main-loop h-stores ----
  if (tid < 64) {
    int n  = tid >> 1;
    int jc = (tid & 1) * 4;
    const float* hp = h0 + (size_t)(n0 + n) * Hh + jc0 + jc;
    u64 pk = (u64)f2b(hp[0]) | ((u64)f2b(hp[1]) << 16) |
             ((u64)f2b(hp[2]) << 32) | ((u64)f2b(hp[3]) << 48);
    __hip_atomic_store((u64*)(hb0 + n * Hh + jc0 + jc), pk,
                       __ATOMIC_RELAXED, __HIP_MEMORY_SCOPE_AGENT);
    asm volatile("s_waitcnt vmcnt(0)" ::: "memory");
    if (tid == 0)
      __hip_atomic_store(&tFlg[r], 1u, __ATOMIC_RELAXED, __HIP_MEMORY_SCOPE_AGENT);
  }
  __syncthreads();  // Bt + pubcnt ready (one-time full sync)

  // epilogue roles: thread owns (nE = tid>>3, jj = tid&7)
  const int jj = tid & 7;
  const int nE = tid >> 3;
  const float bI = bias[0 * 1024 + jc0 + jj];
  const float bF = bias[1 * 1024 + jc0 + jj];
  const float bO = bias[2 * 1024 + jc0 + jj];
  const float bG = bias[3 * 1024 + jc0 + jj];
  float c_reg = 0.f;

  // MFMA lane roles; wave owns K-slice [256w, 256w+256)
  const int arow = l & 15;
  const int kg   = (l >> 4) * 8;
  const int kb   = w * 256;
  const int sw   = (l & 7) << 3;
  const u16* bp0 = &Bt[l & 15][0];
  const u16* bp1 = &Bt[16 | (l & 15)][0];

  // ---- hoist loop-invariant B-fragments ----
  short8 bh0[8], bh1[8], bx0[8], bx1[8];
  #pragma unroll
  for (int i = 0; i < 8; ++i) {
    int ka = (kb + kg + 32 * i) ^ sw;
    bh0[i] = *reinterpret_cast<const short8*>(bp0 + ka);
    bh1[i] = *reinterpret_cast<const short8*>(bp1 + ka);
    int kx = (1024 + kb + kg + 32 * i) ^ sw;
    bx0[i] = *reinterpret_cast<const short8*>(bp0 + kx);
    bx1[i] = *reinterpret_cast<const short8*>(bp1 + kx);
  }

  for (int t = 0; t < Tt; ++t) {
    const u16* hb  = HIST ? hb0 + (size_t)t * (MS * Hh)
                          : hb0 + (t & 1) * (MS * Hh);
    u16*       hbn = HIST ? hb0 + (size_t)(t + 1) * (MS * Hh)
                          : hb0 + ((t + 1) & 1) * (MS * Hh);

    // ---- x-fragment loads (pre-gate; latency hides under wait) ----
    short8 xv0[8], xv1[8];
    if constexpr (XBF16) {
      const u16* xr0 = xb + ((size_t)(n0 + arow)      * Tt + t) * Dd + kb + kg;
      const u16* xr1 = xb + ((size_t)(n0 + 16 + arow) * Tt + t) * Dd + kb + kg;
      #pragma unroll
      for (int i = 0; i < 8; ++i) {
        xv0[i] = *reinterpret_cast<const short8*>(xr0 + 32 * i);
        xv1[i] = *reinterpret_cast<const short8*>(xr1 + 32 * i);
      }
    } else {
      const float* xr0 = x + ((size_t)(n0 + arow)      * Tt + t) * Dd + kb + kg;
      const float* xr1 = x + ((size_t)(n0 + 16 + arow) * Tt + t) * Dd + kb + kg;
      #pragma unroll
      for (int i = 0; i < 8; ++i) {
        float4 a0 = *reinterpret_cast<const float4*>(xr0 + 32 * i);
        float4 a1 = *reinterpret_cast<const float4*>(xr0 + 32 * i + 4);
        float4 c0 = *reinterpret_cast<const float4*>(xr1 + 32 * i);
        float4 c1 = *reinterpret_cast<const float4*>(xr1 + 32 * i + 4);
        short8 v0, v1;
        v0[0]=(short)f2b(a0.x); v0[1]=(short)f2b(a0.y);
        v0[2]=(short)f2b(a0.z); v0[3]=(short)f2b(a0.w);
        v0[4]=(short)f2b(a1.x); v0[5]=(short)f2b(a1.y);
        v0[6]=(short)f2b(a1.z); v0[7]=(short)f2b(a1.w);
        v1[0]=(short)f2b(c0.x); v1[1]=(short)f2b(c0.y);
        v1[2]=(short)f2b(c0.z); v1[3]=(short)f2b(c0.w);
        v1[4]=(short)f2b(c1.x); v1[5]=(short)f2b(c1.y);
        v1[6]=(short)f2b(c1.z); v1[7]=(short)f2b(c1.w);
        xv0[i] = v0; xv1[i] = v1;
      }
    }

    f32x4 a00 = {0.f,0.f,0.f,0.f}, a01 = {0.f,0.f,0.f,0.f};
    f32x4 a10 = {0.f,0.f,0.f,0.f}, a11 = {0.f,0.f,0.f,0.f};

    // ---- x MFMAs PRE-gate (independent of h_t) ----
    #pragma unroll
    for (int i = 0; i < 8; ++i) {
      a00 = __builtin_amdgcn_mfma_f32_16x16x32_bf16(xv0[i], bx0[i], a00, 0, 0, 0);
      a01 = __builtin_amdgcn_mfma_f32_16x16x32_bf16(xv0[i], bx1[i], a01, 0, 0, 0);
      a10 = __builtin_amdgcn_mfma_f32_16x16x32_bf16(xv1[i], bx0[i], a10, 0, 0, 0);
      a11 = __builtin_amdgcn_mfma_f32_16x16x32_bf16(xv1[i], bx1[i], a11, 0, 0, 0);
    }

    // ---- Gate A: per-wave poll of its 32 producers (r8 style) ----
    {
      const unsigned ep = (unsigned)(t + 1);
      bool rdy;
      do {
        unsigned f = 0xFFFFFFFFu;
        if (l < 32)
          f = __hip_atomic_load(&tFlg[32 * w + l], __ATOMIC_RELAXED,
                                __HIP_MEMORY_SCOPE_AGENT);
        rdy = (bool)__all(f >= ep);
        if (!rdy) __builtin_amdgcn_s_sleep(1);
      } while (!rdy);
    }
    // ---- Gate B: own-wg waves finished prior iteration (ex WAR safety) ----
    while (__hip_atomic_load(&pubcnt, __ATOMIC_RELAXED,
                             __HIP_MEMORY_SCOPE_WORKGROUP) < (unsigned)(4 * t))
      __builtin_amdgcn_s_sleep(1);
    asm volatile("" ::: "memory");  // keep h loads below the gates

    // ---- h loads: HIST -> normal cached (fresh addr) ----
    short8 hv0[8], hv1[8];
    {
      const u16* hr = hb + (size_t)arow * Hh + kb + kg;
      #pragma unroll
      for (int i = 0; i < 8; ++i) {
        if constexpr (HIST) {
          hv0[i] = *reinterpret_cast<const short8*>(hr + 32 * i);
          hv1[i] = *reinterpret_cast<const short8*>(hr + 16 * Hh + 32 * i);
        } else {
          hv0[i] = ldh16(hr + 32 * i);
          hv1[i] = ldh16(hr + 16 * Hh + 32 * i);
        }
      }
    }

    // ---- h MFMAs ----
    #pragma unroll
    for (int i = 0; i < 8; ++i) {
      a00 = __builtin_amdgcn_mfma_f32_16x16x32_bf16(hv0[i], bh0[i], a00, 0, 0, 0);
      a01 = __builtin_amdgcn_mfma_f32_16x16x32_bf16(hv0[i], bh1[i], a01, 0, 0, 0);
      a10 = __builtin_amdgcn_mfma_f32_16x16x32_bf16(hv1[i], bh0[i], a10, 0, 0, 0);
      a11 = __builtin_amdgcn_mfma_f32_16x16x32_bf16(hv1[i], bh1[i], a11, 0, 0, 0);
    }

    // ---- partial sums -> LDS ----
    #pragma unroll
    for (int q = 0; q < 4; ++q) {
      ex[w][ 0 + (l >> 4) * 4 + q][ 0 + (l & 15)] = a00[q];
      ex[w][ 0 + (l >> 4) * 4 + q][16 + (l & 15)] = a01[q];
      ex[w][16 + (l >> 4) * 4 + q][ 0 + (l & 15)] = a10[q];
      ex[w][16 + (l >> 4) * 4 + q][16 + (l & 15)] = a11[q];
    }
    bar_w();  // the ONLY per-step barrier

    // ---- gates, state update (thread owns row nE, col jj) ----
    float pI = bI, pF = bF, pO = bO, pG = bG;
    #pragma unroll
    for (int wv = 0; wv < 4; ++wv) {
      pI += ex[wv][nE][ 0 + jj];
      pF += ex[wv][nE][ 8 + jj];
      pO += ex[wv][nE][16 + jj];
      pG += ex[wv][nE][24 + jj];
    }
    const float ig = sigm(pI), fg = sigm(pF), og = sigm(pO);
    const float gg = tanhfast(pG);
    c_reg = fg * c_reg + ig * gg;
    const float hv = og * tanhfast(c_reg);

    // ---- symmetric publish: lane-pair u32 SC1 store of own h ----
    {
      int hb16 = (int)f2b(hv);
      int pb   = __shfl_xor(hb16, 1, 64);   // partner holds jj^1
      if ((tid & 1) == 0) {
        unsigned pk = (unsigned)(hb16 & 0xFFFF) | ((unsigned)(pb & 0xFFFF) << 16);
        __hip_atomic_store((unsigned*)(hbn + nE * Hh + jc0 + jj), pk,
                           __ATOMIC_RELAXED, __HIP_MEMORY_SCOPE_AGENT);
      }
      asm volatile("s_waitcnt vmcnt(0)" ::: "memory");  // own stores ACKed
      if (l == 0) {
        unsigned old = __hip_atomic_fetch_add(&pubcnt, 1u, __ATOMIC_RELAXED,
                                              __HIP_MEMORY_SCOPE_WORKGROUP);
        if (old == (unsigned)(4 * t + 3) && t + 1 < Tt)   // 4th wave: flag
          __hip_atomic_store(&tFlg[r], (unsigned)(t + 2),
                             __ATOMIC_RELAXED, __HIP_MEMORY_SCOPE_AGENT);
      }
    }

    // ---- out store (off critical path; drained ~1 step later) ----
    out[((size_t)(n0 + nE) * Tt + t) * Hh + jc0 + jj] = hv;
  }
}

extern "C" void kernel_launch(void* const* d_in, const int* in_sizes, int n_in,
                              void* d_out, int out_size, void* d_ws, size_t ws_size,
                              hipStream_t stream) {
  const float* x    = (const float*)d_in[0];
  const float* h0   = (const float*)d_in[1];
  const float* Wx   = (const float*)d_in[2];
  const float* Wh   = (const float*)d_in[3];
  const float* bias = (const float*)d_in[4];
  float* out = (float*)d_out;

  char* wsb = (char*)d_ws;
  unsigned* flg = (unsigned*)wsb;                  // 2 teams x 128 u32 = 1 KiB

  const size_t hist_off   = (size_t)1 << 20;
  const size_t hist_bytes = (size_t)2 * Tt * MS * Hh * 2;       // 128 MiB
  const size_t xb_bytes   = (size_t)Nb * Tt * Dd * 2;           // 128 MiB

  const bool use_hist = ws_size >= hist_off + hist_bytes;
  const size_t xb_off = use_hist ? hist_off + hist_bytes : hist_off;
  const bool use_xb   = ws_size >= xb_off + xb_bytes;

  u16* hmem = use_hist ? (u16*)(wsb + hist_off) : (u16*)(wsb + 65536);
  u16* xb   = (u16*)(wsb + xb_off);

  hipMemsetAsync(wsb, 0, 40960, stream);           // clear flags each launch

  void* args[] = {(void*)&x, (void*)&xb, (void*)&h0, (void*)&Wx, (void*)&Wh,
                  (void*)&bias, (void*)&out, (void*)&hmem, (void*)&flg};
  if (use_xb)
    cvt_x_kernel<<<dim3((Nb * Tt * Dd) / (8 * TPB)), dim3(TPB), 0, stream>>>(x, xb);

  const void* kfn =
      use_hist ? (use_xb ? (const void*)lstm_team<true, true>
                         : (const void*)lstm_team<false, true>)
               : (use_xb ? (const void*)lstm_team<true, false>
                         : (const void*)lstm_team<false, false>);
  hipLaunchCooperativeKernel(kfn, dim3(NWG), dim3(TPB), args, 0, stream);
}